// Round 8
// baseline (1150.754 us; speedup 1.0000x reference)
//
#include <hip/hip_runtime.h>
#include <hip/hip_bf16.h>

// Problem constants
#define B_ 4
#define T_ 200
#define U_ 100
#define ENC_DIM 512
#define JDIM 640
#define VOCAB 1024
#define M_TOTAL (B_*T_*U_)   // 80000

typedef __attribute__((ext_vector_type(8))) short short8;
typedef __attribute__((ext_vector_type(4))) float float4v;
typedef __attribute__((ext_vector_type(4))) unsigned short ushort4v;
typedef __attribute__((ext_vector_type(8))) unsigned short ushort8v;

__device__ __forceinline__ unsigned short f2bf(float x) {
    unsigned u = __builtin_bit_cast(unsigned, x);
    u += 0x7fffu + ((u >> 16) & 1u);   // round-to-nearest-even
    return (unsigned short)(u >> 16);
}

__device__ __forceinline__ float fast_tanh(float x) {
    return 1.0f - 2.0f / (__expf(2.0f * x) + 1.0f);
}

__device__ __forceinline__ void gload_lds16(const void* g, void* l) {
    __builtin_amdgcn_global_load_lds(
        (const __attribute__((address_space(1))) unsigned int*)g,
        (__attribute__((address_space(3))) unsigned int*)l, 16, 0, 0);
}

// ---------------------------------------------------------------------------
// prep: one launch doing enc-proj, pred-proj, and W_out transpose+cast.
// ---------------------------------------------------------------------------
#define PJ_BM 32
#define PJ_BN 128
#define PJ_BK 32
#define NCB   (JDIM / PJ_BN)          // 5
#define ENC_RB 25                     // 800/32
#define PRED_RB 13                    // ceil(400/32)
#define ENC_BLOCKS  (ENC_RB * NCB)    // 125
#define PRED_BLOCKS (PRED_RB * NCB)   // 65
#define TC_BLOCKS   (20 * 32)         // 640
#define PREP_BLOCKS (ENC_BLOCKS + PRED_BLOCKS + TC_BLOCKS)  // 830

#define XS_LD 36    // 32 k + 4 pad (floats)
#define WS_LD 132   // 128 n + 4 pad (floats)

__global__ __launch_bounds__(256)
void prep(const float* __restrict__ enc_out, const float* __restrict__ pred_out,
          const float* __restrict__ W_enc, const float* __restrict__ b_enc,
          const float* __restrict__ W_pred, const float* __restrict__ W_out,
          float* __restrict__ encp, float* __restrict__ predp,
          unsigned short* __restrict__ Wt)
{
    __shared__ float smem[PJ_BM * XS_LD + PJ_BK * WS_LD];  // 21.5 KB
    const int bid = blockIdx.x;
    const int tid = threadIdx.x;

    if (bid < ENC_BLOCKS + PRED_BLOCKS) {
        // ---- projection branch ----
        const float* X; const float* W; const float* bias; float* Y; int M; int lb;
        if (bid < ENC_BLOCKS) {
            X = enc_out; W = W_enc; bias = b_enc; Y = encp; M = 800; lb = bid;
        } else {
            X = pred_out; W = W_pred; bias = nullptr; Y = predp; M = 400; lb = bid - ENC_BLOCKS;
        }
        const int row0 = (lb / NCB) * PJ_BM;
        const int col0 = (lb % NCB) * PJ_BN;

        float* Xs = smem;                    // [32][36]
        float* Ws = smem + PJ_BM * XS_LD;    // [32][132]

        const int xr = tid >> 3;             // 0..31
        const int xk = (tid & 7) * 4;        // 0..28
        const int wrow = tid >> 5;           // 0..7 (+8r)
        const int wcol = (tid & 31) * 4;     // 0..124
        const int ty = tid >> 4;             // 0..15 -> rows ty, ty+16
        const int tx = tid & 15;             // cols tx*4, tx*4+64

        int xrow = row0 + xr; if (xrow >= M) xrow = M - 1;

        float4v acc00 = {0,0,0,0}, acc01 = {0,0,0,0};
        float4v acc10 = {0,0,0,0}, acc11 = {0,0,0,0};

        for (int k0 = 0; k0 < ENC_DIM; k0 += PJ_BK) {
            *(float4v*)&Xs[xr * XS_LD + xk] =
                *(const float4v*)(X + (size_t)xrow * ENC_DIM + k0 + xk);
            #pragma unroll
            for (int r = 0; r < 4; ++r)
                *(float4v*)&Ws[(wrow + 8*r) * WS_LD + wcol] =
                    *(const float4v*)(W + (size_t)(k0 + wrow + 8*r) * JDIM + col0 + wcol);
            __syncthreads();
            #pragma unroll
            for (int k4 = 0; k4 < PJ_BK / 4; ++k4) {
                float4v a0 = *(const float4v*)&Xs[ty * XS_LD + k4*4];
                float4v a1 = *(const float4v*)&Xs[(ty + 16) * XS_LD + k4*4];
                #pragma unroll
                for (int q = 0; q < 4; ++q) {
                    float4v w0 = *(const float4v*)&Ws[(k4*4 + q) * WS_LD + tx*4];
                    float4v w1 = *(const float4v*)&Ws[(k4*4 + q) * WS_LD + tx*4 + 64];
                    float a0q = a0[q], a1q = a1[q];
                    acc00 += w0 * a0q;  acc01 += w1 * a0q;
                    acc10 += w0 * a1q;  acc11 += w1 * a1q;
                }
            }
            __syncthreads();
        }

        const int c0 = col0 + tx*4, c1 = c0 + 64;
        float4v bb0 = {0,0,0,0}, bb1 = {0,0,0,0};
        if (bias) { bb0 = *(const float4v*)(bias + c0); bb1 = *(const float4v*)(bias + c1); }
        int r0 = row0 + ty, r1 = row0 + ty + 16;
        if (r0 < M) {
            *(float4v*)(Y + (size_t)r0 * JDIM + c0) = acc00 + bb0;
            *(float4v*)(Y + (size_t)r0 * JDIM + c1) = acc01 + bb1;
        }
        if (r1 < M) {
            *(float4v*)(Y + (size_t)r1 * JDIM + c0) = acc10 + bb0;
            *(float4v*)(Y + (size_t)r1 * JDIM + c1) = acc11 + bb1;
        }
    } else {
        // ---- transpose+cast branch: Wt[n][k] = bf16(W_out[k][n]) ----
        float (*tile)[33] = (float(*)[33])smem;
        const int local = bid - (ENC_BLOCKS + PRED_BLOCKS);
        const int bk = local % 20;
        const int bn = local / 20;
        const int tx = tid & 31;
        const int ty = tid >> 5;
        #pragma unroll
        for (int i = 0; i < 32; i += 8)
            tile[ty + i][tx] = W_out[(size_t)(bk * 32 + ty + i) * VOCAB + bn * 32 + tx];
        __syncthreads();
        #pragma unroll
        for (int i = 0; i < 32; i += 8)
            Wt[(size_t)(bn * 32 + ty + i) * JDIM + bk * 32 + tx] = f2bf(tile[tx][ty + i]);
    }
}

// ---------------------------------------------------------------------------
// joint_tanh: jbuf[m-m0][k] = bf16(tanh(encp[row(m)][k] + predp[row(m)][k]))
// ---------------------------------------------------------------------------
__global__ __launch_bounds__(256)
void joint_tanh(const float* __restrict__ encp, const float* __restrict__ predp,
                unsigned short* __restrict__ jbuf, int m0, int mcount) {
    int idx = blockIdx.x * 256 + threadIdx.x;
    if (idx >= mcount * (JDIM / 8)) return;
    int m  = idx / (JDIM / 8);
    int c8 = (idx - m * (JDIM / 8)) * 8;
    int mg = m0 + m;
    int b   = mg / (T_ * U_);
    int rem = mg - b * (T_ * U_);
    int t   = rem / U_;
    int u   = rem - t * U_;
    const float* eRow = encp  + (size_t)(b * T_ + t) * JDIM + c8;
    const float* pRow = predp + (size_t)(b * U_ + u) * JDIM + c8;
    float4v e0 = *(const float4v*)(eRow);
    float4v e1 = *(const float4v*)(eRow + 4);
    float4v p0 = *(const float4v*)(pRow);
    float4v p1 = *(const float4v*)(pRow + 4);
    ushort8v v;
    v.s0 = f2bf(fast_tanh(e0.x + p0.x));
    v.s1 = f2bf(fast_tanh(e0.y + p0.y));
    v.s2 = f2bf(fast_tanh(e0.z + p0.z));
    v.s3 = f2bf(fast_tanh(e0.w + p0.w));
    v.s4 = f2bf(fast_tanh(e1.x + p1.x));
    v.s5 = f2bf(fast_tanh(e1.y + p1.y));
    v.s6 = f2bf(fast_tanh(e1.z + p1.z));
    v.s7 = f2bf(fast_tanh(e1.w + p1.w));
    *(ushort8v*)(jbuf + (size_t)m * JDIM + c8) = v;
}

// ---------------------------------------------------------------------------
// Pure bf16 GEMM: out = A @ Wt^T + b_out
// A: [mc,640] bf16 k-contig.  Wt: [1024,640] bf16 k-contig.
// BM=BN=128, BK=32, 4-buffer ring, prefetch depth 2, counted vmcnt(4) (T4):
//   prologue: STAGE(buf0,t0); STAGE(buf1,t1)            [8 loads in flight]
//   iter t:   vmcnt(4) [tile-t landed]; s_barrier;
//             STAGE(buf[(t+2)&3], t+2);                  [back to 8 in flight]
//             COMPUTE(buf[t&3]);
// Race-safety: barrier(t) => all waves completed compute(t-1) (program order)
// => compute(t-2) complete => STAGE(t+2) overwriting buf[(t-2)&3] is safe.
// Each wave's own vmcnt(4) + the barrier covers ALL waves' tile-t loads.
// T2 swizzle (4 chunks/row): global src chunk = slot^(row&3); read slot =
// quad^(lm&3) -> 8 lanes per 4-bank slot x 8 slots = optimal 8-clk b128.
// Epilogue: acc -> LDS transposed epi[col][row] (stride 136, b128 writes at
// optimal 8 clk, bias folded in), then dense dwordx4 nontemporal row stores
// (each thread streams 256 contiguous bytes) -> kills the 27% write-amp of
// the old 4-row x 64 B scattered dword stores.
// ---------------------------------------------------------------------------
#define GBM 128
#define GBN 128
#define GBK 32
#define NBN (VOCAB / GBN)     // 8
#define NTILES (JDIM / GBK)   // 20
#define EPI_LD 136            // floats; 16B-aligned cols, odd/32-friendly banks

__global__ __launch_bounds__(256, 2)
void gemm_joint(const unsigned short* __restrict__ A,
                const unsigned short* __restrict__ Wt,
                const float* __restrict__ bout,
                float* __restrict__ out)
{
    // staging: As 4 bufs x 8 KB (32 KB) + Bs 4 bufs x 8 KB (32 KB) = 64 KB
    // epilogue: 128 cols x 136 floats = 69632 B  -> union size 69632
    __shared__ __align__(16) unsigned char smem[GBN * EPI_LD * 4];
    unsigned short* asB = (unsigned short*)smem;            // [4][128*32]
    unsigned short* bsB = asB + 4 * GBM * GBK;              // [4][128*32]
    float* epi = (float*)smem;                              // [128][136]

    const int tid = threadIdx.x;

    // XCD-aware swizzle (bijective: gridDim.x = nbm*8, always % 8 == 0).
    const int cpx = gridDim.x >> 3;
    const int bid = blockIdx.x;
    const int swz = (bid & 7) * cpx + (bid >> 3);
    const int bm = swz >> 3;          // NBN == 8
    const int bn = swz & (NBN - 1);

    // staging: thread covers row (tid>>2)+64r, chunk tid&3 (16B);
    // LDS dst = tid*16B + r*4KB (lane-linear); global chunk pre-XOR'd.
    const int srow = tid >> 2;        // 0..63
    const int schunk = tid & 3;
    const int scolSwz = (schunk ^ (srow & 3)) * 8;
    const unsigned short* aBase = A  + (size_t)(bm * GBM + srow) * JDIM + scolSwz;
    const unsigned short* bBase = Wt + (size_t)(bn * GBN + srow) * JDIM + scolSwz;
    const int ldsOff = tid * 8;       // shorts

    const int wave = tid >> 6, lane = tid & 63;
    const int wm = (wave >> 1) * 64, wn = (wave & 1) * 64;
    const int lm = lane & 15, quad = lane >> 4;
    const int cswz = (quad ^ (lm & 3)) * 8;   // read-side swizzled k-offset (shorts)

    // bias per j-frag (col = bn*128 + wn + j*16 + lm)
    float biasj[4];
    #pragma unroll
    for (int j = 0; j < 4; ++j)
        biasj[j] = bout[bn * GBN + wn + j * 16 + lm];

    float4v acc[4][4];
    #pragma unroll
    for (int i = 0; i < 4; ++i)
        #pragma unroll
        for (int j = 0; j < 4; ++j)
            acc[i][j] = (float4v){0.f, 0.f, 0.f, 0.f};

#define STAGE(buf, t)                                                           \
    {                                                                           \
        const int k0_ = (t) * GBK;                                              \
        _Pragma("unroll")                                                       \
        for (int r = 0; r < 2; ++r) {                                           \
            gload_lds16(aBase + (size_t)(r * 64) * JDIM + k0_,                  \
                        asB + (buf) * (GBM * GBK) + ldsOff + r * 2048);         \
            gload_lds16(bBase + (size_t)(r * 64) * JDIM + k0_,                  \
                        bsB + (buf) * (GBM * GBK) + ldsOff + r * 2048);         \
        }                                                                       \
    }

#define COMPUTE(buf)                                                            \
    {                                                                           \
        short8 a[4], b[4];                                                      \
        _Pragma("unroll")                                                       \
        for (int i = 0; i < 4; ++i)                                             \
            a[i] = *(const short8*)(asB + (buf) * (GBM * GBK) + (wm + i * 16 + lm) * GBK + cswz); \
        _Pragma("unroll")                                                       \
        for (int j = 0; j < 4; ++j)                                             \
            b[j] = *(const short8*)(bsB + (buf) * (GBM * GBK) + (wn + j * 16 + lm) * GBK + cswz); \
        _Pragma("unroll")                                                       \
        for (int i = 0; i < 4; ++i)                                             \
            _Pragma("unroll")                                                   \
            for (int j = 0; j < 4; ++j)                                         \
                acc[i][j] = __builtin_amdgcn_mfma_f32_16x16x32_bf16(a[i], b[j], acc[i][j], 0, 0, 0); \
    }

    // prologue: 2 tiles in flight
    STAGE(0, 0);
    STAGE(1, 1);

    for (int t = 0; t < NTILES; ++t) {
        if (t < NTILES - 1)
            asm volatile("s_waitcnt vmcnt(4)" ::: "memory");   // tile t landed, t+1 may fly
        else
            asm volatile("s_waitcnt vmcnt(0)" ::: "memory");   // final drain
        __builtin_amdgcn_s_barrier();
        if (t + 2 < NTILES)
            STAGE((t + 2) & 3, t + 2);
        COMPUTE(t & 3);
    }

#undef STAGE
#undef COMPUTE

    // ---- epilogue: LDS-transposed coalesced store ----
    __syncthreads();   // all waves done reading staging LDS

    #pragma unroll
    for (int i = 0; i < 4; ++i)
        #pragma unroll
        for (int j = 0; j < 4; ++j) {
            float4v v = acc[i][j];
            v.x += biasj[j]; v.y += biasj[j]; v.z += biasj[j]; v.w += biasj[j];
            // epi[col][rowbase..rowbase+3]  (rows are the 4 acc regs -> b128)
            *(float4v*)&epi[(wn + j * 16 + lm) * EPI_LD + wm + i * 16 + quad * 4] = v;
        }

    __syncthreads();

    // read back: thread owns out-row r = tid>>1, col half h = tid&1 (64 cols)
    {
        const int r = tid >> 1;
        const int h = tid & 1;
        float* dst = out + (size_t)(bm * GBM + r) * VOCAB + bn * GBN + h * 64;
        #pragma unroll
        for (int cc = 0; cc < 16; ++cc) {
            const int c = h * 64 + cc * 4;
            float4v v = { epi[(c + 0) * EPI_LD + r], epi[(c + 1) * EPI_LD + r],
                          epi[(c + 2) * EPI_LD + r], epi[(c + 3) * EPI_LD + r] };
            __builtin_nontemporal_store(v, (float4v*)(dst + cc * 4));
        }
    }
}

// ---------------------------------------------------------------------------
// Fallback (ws too small): fused kernel — tanh recomputed per N-tile.
// ---------------------------------------------------------------------------
#define BM 128
#define BN 128
#define BK 64
#define LDST 72

__global__ __launch_bounds__(256, 2)
void joint_gemm_fused(const float* __restrict__ encp, const float* __restrict__ predp,
                      const unsigned short* __restrict__ Wt, const float* __restrict__ bout,
                      float* __restrict__ out)
{
    __shared__ __align__(16) unsigned short As[BM * LDST];
    __shared__ __align__(16) unsigned short Bs[BN * LDST];
    const int tid = threadIdx.x;
    const int bm = blockIdx.x, bn = blockIdx.y;
    const int rbase = tid >> 4;
    const int c4 = (tid & 15) * 4;
    int encOff[8], predOff[8];
    #pragma unroll
    for (int i = 0; i < 8; ++i) {
        int mg  = bm * BM + i * 16 + rbase;
        int b   = mg / (T_ * U_);
        int rem = mg - b * (T_ * U_);
        int t   = rem / U_;
        int u   = rem - t * U_;
        encOff[i]  = (b * T_ + t) * JDIM + c4;
        predOff[i] = (b * U_ + u) * JDIM + c4;
    }
    const int nrow = tid >> 3;
    const int bk8  = (tid & 7) * 8;
    const size_t wtBase = (size_t)(bn * BN) * JDIM;
    const int wave = tid >> 6, lane = tid & 63;
    const int wm = (wave >> 1) * 64, wn = (wave & 1) * 64;
    const int lm = lane & 15, quad = lane >> 4;

    float4v acc[4][4];
    #pragma unroll
    for (int i = 0; i < 4; ++i)
        #pragma unroll
        for (int j = 0; j < 4; ++j)
            acc[i][j] = (float4v){0.f, 0.f, 0.f, 0.f};

    for (int k0 = 0; k0 < JDIM; k0 += BK) {
        #pragma unroll
        for (int i = 0; i < 8; ++i) {
            int row = i * 16 + rbase;
            float4v e4 = *(const float4v*)(encp + encOff[i] + k0);
            float4v p4 = *(const float4v*)(predp + predOff[i] + k0);
            ushort4v v;
            v.x = f2bf(fast_tanh(e4.x + p4.x));
            v.y = f2bf(fast_tanh(e4.y + p4.y));
            v.z = f2bf(fast_tanh(e4.z + p4.z));
            v.w = f2bf(fast_tanh(e4.w + p4.w));
            *(ushort4v*)(&As[row * LDST + c4]) = v;
        }
        #pragma unroll
        for (int i = 0; i < 4; ++i) {
            int n = i * 32 + nrow;
            float4v w = *(const float4v*)((const float*)(Wt + wtBase + (size_t)n * JDIM + k0 + bk8));
            *(float4v*)(&Bs[n * LDST + bk8]) = w;
        }
        __syncthreads();
        #pragma unroll
        for (int kk = 0; kk < BK; kk += 32) {
            short8 a[4], b[4];
            #pragma unroll
            for (int i = 0; i < 4; ++i)
                a[i] = *(const short8*)(&As[(wm + i * 16 + lm) * LDST + kk + quad * 8]);
            #pragma unroll
            for (int j = 0; j < 4; ++j)
                b[j] = *(const short8*)(&Bs[(wn + j * 16 + lm) * LDST + kk + quad * 8]);
            #pragma unroll
            for (int i = 0; i < 4; ++i)
                #pragma unroll
                for (int j = 0; j < 4; ++j)
                    acc[i][j] = __builtin_amdgcn_mfma_f32_16x16x32_bf16(a[i], b[j], acc[i][j], 0, 0, 0);
        }
        __syncthreads();
    }
    #pragma unroll
    for (int j = 0; j < 4; ++j) {
        int ng = bn * BN + wn + j * 16 + lm;
        float bias = bout[ng];
        #pragma unroll
        for (int i = 0; i < 4; ++i) {
            int mg0 = bm * BM + wm + i * 16 + quad * 4;
            #pragma unroll
            for (int r = 0; r < 4; ++r)
                out[(size_t)(mg0 + r) * VOCAB + ng] = acc[i][j][r] + bias;
        }
    }
}

// ---------------------------------------------------------------------------
extern "C" void kernel_launch(void* const* d_in, const int* in_sizes, int n_in,
                              void* d_out, int out_size, void* d_ws, size_t ws_size,
                              hipStream_t stream) {
    const float* enc_out  = (const float*)d_in[0];  // [4,200,512]
    const float* pred_out = (const float*)d_in[1];  // [4,100,512]
    const float* W_enc    = (const float*)d_in[2];  // [512,640]
    const float* b_enc    = (const float*)d_in[3];  // [640]
    const float* W_pred   = (const float*)d_in[4];  // [512,640]
    const float* W_out    = (const float*)d_in[5];  // [640,1024]
    const float* b_out    = (const float*)d_in[6];  // [1024]
    float* out = (float*)d_out;

    float* encp  = (float*)d_ws;                                 // 800*640 fp32
    float* predp = encp + 800 * JDIM;                            // 400*640 fp32
    unsigned short* Wt = (unsigned short*)(predp + 400 * JDIM);  // 1024*640 bf16
    unsigned short* jbuf = Wt + (size_t)VOCAB * JDIM;            // chunked joint bf16

    const size_t fixedBytes = (800 * JDIM + 400 * JDIM) * sizeof(float)
                            + (size_t)VOCAB * JDIM * sizeof(unsigned short);

    prep<<<dim3(PREP_BLOCKS), 256, 0, stream>>>(enc_out, pred_out, W_enc, b_enc,
                                                W_pred, W_out, encp, predp, Wt);

    size_t avail = ws_size > fixedBytes ? ws_size - fixedBytes : 0;
    long mcMax = (long)(avail / (JDIM * sizeof(unsigned short)));
    mcMax = (mcMax / 128) * 128;
    if (mcMax > M_TOTAL) mcMax = M_TOTAL;

    if (mcMax >= 8192) {
        for (int m0 = 0; m0 < M_TOTAL; m0 += (int)mcMax) {
            int mc = M_TOTAL - m0 < mcMax ? M_TOTAL - m0 : (int)mcMax;  // always mult of 128
            int nThreads = mc * (JDIM / 8);
            joint_tanh<<<(nThreads + 255) / 256, 256, 0, stream>>>(encp, predp, jbuf, m0, mc);
            gemm_joint<<<dim3((mc / GBM) * NBN), 256, 0, stream>>>(jbuf, Wt, b_out,
                                                                   out + (size_t)m0 * VOCAB);
        }
    } else {
        // scratch too small for materialization — fused path
        joint_gemm_fused<<<dim3(M_TOTAL / BM, VOCAB / BN), 256, 0, stream>>>(encp, predp, Wt, b_out, out);
    }
}

// Round 9
// 444.626 us; speedup vs baseline: 2.5881x; 2.5881x over previous
//
#include <hip/hip_runtime.h>
#include <hip/hip_bf16.h>

// Problem constants
#define B_ 4
#define T_ 200
#define U_ 100
#define ENC_DIM 512
#define JDIM 640
#define VOCAB 1024
#define M_TOTAL (B_*T_*U_)   // 80000

typedef __attribute__((ext_vector_type(8))) short short8;
typedef __attribute__((ext_vector_type(4))) float float4v;
typedef __attribute__((ext_vector_type(4))) unsigned short ushort4v;
typedef __attribute__((ext_vector_type(8))) unsigned short ushort8v;

__device__ __forceinline__ unsigned short f2bf(float x) {
    unsigned u = __builtin_bit_cast(unsigned, x);
    u += 0x7fffu + ((u >> 16) & 1u);   // round-to-nearest-even
    return (unsigned short)(u >> 16);
}

__device__ __forceinline__ float fast_tanh(float x) {
    return 1.0f - 2.0f / (__expf(2.0f * x) + 1.0f);
}

__device__ __forceinline__ void gload_lds16(const void* g, void* l) {
    __builtin_amdgcn_global_load_lds(
        (const __attribute__((address_space(1))) unsigned int*)g,
        (__attribute__((address_space(3))) unsigned int*)l, 16, 0, 0);
}

// ---------------------------------------------------------------------------
// prep: one launch doing enc-proj, pred-proj, and W_out transpose+cast.
// ---------------------------------------------------------------------------
#define PJ_BM 32
#define PJ_BN 128
#define PJ_BK 32
#define NCB   (JDIM / PJ_BN)          // 5
#define ENC_RB 25                     // 800/32
#define PRED_RB 13                    // ceil(400/32)
#define ENC_BLOCKS  (ENC_RB * NCB)    // 125
#define PRED_BLOCKS (PRED_RB * NCB)   // 65
#define TC_BLOCKS   (20 * 32)         // 640
#define PREP_BLOCKS (ENC_BLOCKS + PRED_BLOCKS + TC_BLOCKS)  // 830

#define XS_LD 36    // 32 k + 4 pad (floats)
#define WS_LD 132   // 128 n + 4 pad (floats)

__global__ __launch_bounds__(256)
void prep(const float* __restrict__ enc_out, const float* __restrict__ pred_out,
          const float* __restrict__ W_enc, const float* __restrict__ b_enc,
          const float* __restrict__ W_pred, const float* __restrict__ W_out,
          float* __restrict__ encp, float* __restrict__ predp,
          unsigned short* __restrict__ Wt)
{
    __shared__ float smem[PJ_BM * XS_LD + PJ_BK * WS_LD];  // 21.5 KB
    const int bid = blockIdx.x;
    const int tid = threadIdx.x;

    if (bid < ENC_BLOCKS + PRED_BLOCKS) {
        // ---- projection branch ----
        const float* X; const float* W; const float* bias; float* Y; int M; int lb;
        if (bid < ENC_BLOCKS) {
            X = enc_out; W = W_enc; bias = b_enc; Y = encp; M = 800; lb = bid;
        } else {
            X = pred_out; W = W_pred; bias = nullptr; Y = predp; M = 400; lb = bid - ENC_BLOCKS;
        }
        const int row0 = (lb / NCB) * PJ_BM;
        const int col0 = (lb % NCB) * PJ_BN;

        float* Xs = smem;                    // [32][36]
        float* Ws = smem + PJ_BM * XS_LD;    // [32][132]

        const int xr = tid >> 3;             // 0..31
        const int xk = (tid & 7) * 4;        // 0..28
        const int wrow = tid >> 5;           // 0..7 (+8r)
        const int wcol = (tid & 31) * 4;     // 0..124
        const int ty = tid >> 4;             // 0..15 -> rows ty, ty+16
        const int tx = tid & 15;             // cols tx*4, tx*4+64

        int xrow = row0 + xr; if (xrow >= M) xrow = M - 1;

        float4v acc00 = {0,0,0,0}, acc01 = {0,0,0,0};
        float4v acc10 = {0,0,0,0}, acc11 = {0,0,0,0};

        for (int k0 = 0; k0 < ENC_DIM; k0 += PJ_BK) {
            *(float4v*)&Xs[xr * XS_LD + xk] =
                *(const float4v*)(X + (size_t)xrow * ENC_DIM + k0 + xk);
            #pragma unroll
            for (int r = 0; r < 4; ++r)
                *(float4v*)&Ws[(wrow + 8*r) * WS_LD + wcol] =
                    *(const float4v*)(W + (size_t)(k0 + wrow + 8*r) * JDIM + col0 + wcol);
            __syncthreads();
            #pragma unroll
            for (int k4 = 0; k4 < PJ_BK / 4; ++k4) {
                float4v a0 = *(const float4v*)&Xs[ty * XS_LD + k4*4];
                float4v a1 = *(const float4v*)&Xs[(ty + 16) * XS_LD + k4*4];
                #pragma unroll
                for (int q = 0; q < 4; ++q) {
                    float4v w0 = *(const float4v*)&Ws[(k4*4 + q) * WS_LD + tx*4];
                    float4v w1 = *(const float4v*)&Ws[(k4*4 + q) * WS_LD + tx*4 + 64];
                    float a0q = a0[q], a1q = a1[q];
                    acc00 += w0 * a0q;  acc01 += w1 * a0q;
                    acc10 += w0 * a1q;  acc11 += w1 * a1q;
                }
            }
            __syncthreads();
        }

        const int c0 = col0 + tx*4, c1 = c0 + 64;
        float4v bb0 = {0,0,0,0}, bb1 = {0,0,0,0};
        if (bias) { bb0 = *(const float4v*)(bias + c0); bb1 = *(const float4v*)(bias + c1); }
        int r0 = row0 + ty, r1 = row0 + ty + 16;
        if (r0 < M) {
            *(float4v*)(Y + (size_t)r0 * JDIM + c0) = acc00 + bb0;
            *(float4v*)(Y + (size_t)r0 * JDIM + c1) = acc01 + bb1;
        }
        if (r1 < M) {
            *(float4v*)(Y + (size_t)r1 * JDIM + c0) = acc10 + bb0;
            *(float4v*)(Y + (size_t)r1 * JDIM + c1) = acc11 + bb1;
        }
    } else {
        // ---- transpose+cast branch: Wt[n][k] = bf16(W_out[k][n]) ----
        float (*tile)[33] = (float(*)[33])smem;
        const int local = bid - (ENC_BLOCKS + PRED_BLOCKS);
        const int bk = local % 20;
        const int bn = local / 20;
        const int tx = tid & 31;
        const int ty = tid >> 5;
        #pragma unroll
        for (int i = 0; i < 32; i += 8)
            tile[ty + i][tx] = W_out[(size_t)(bk * 32 + ty + i) * VOCAB + bn * 32 + tx];
        __syncthreads();
        #pragma unroll
        for (int i = 0; i < 32; i += 8)
            Wt[(size_t)(bn * 32 + ty + i) * JDIM + bk * 32 + tx] = f2bf(tile[tx][ty + i]);
    }
}

// ---------------------------------------------------------------------------
// joint_tanh: jbuf[m-m0][k] = bf16(tanh(encp[row(m)][k] + predp[row(m)][k]))
// ---------------------------------------------------------------------------
__global__ __launch_bounds__(256)
void joint_tanh(const float* __restrict__ encp, const float* __restrict__ predp,
                unsigned short* __restrict__ jbuf, int m0, int mcount) {
    int idx = blockIdx.x * 256 + threadIdx.x;
    if (idx >= mcount * (JDIM / 8)) return;
    int m  = idx / (JDIM / 8);
    int c8 = (idx - m * (JDIM / 8)) * 8;
    int mg = m0 + m;
    int b   = mg / (T_ * U_);
    int rem = mg - b * (T_ * U_);
    int t   = rem / U_;
    int u   = rem - t * U_;
    const float* eRow = encp  + (size_t)(b * T_ + t) * JDIM + c8;
    const float* pRow = predp + (size_t)(b * U_ + u) * JDIM + c8;
    float4v e0 = *(const float4v*)(eRow);
    float4v e1 = *(const float4v*)(eRow + 4);
    float4v p0 = *(const float4v*)(pRow);
    float4v p1 = *(const float4v*)(pRow + 4);
    ushort8v v;
    v.s0 = f2bf(fast_tanh(e0.x + p0.x));
    v.s1 = f2bf(fast_tanh(e0.y + p0.y));
    v.s2 = f2bf(fast_tanh(e0.z + p0.z));
    v.s3 = f2bf(fast_tanh(e0.w + p0.w));
    v.s4 = f2bf(fast_tanh(e1.x + p1.x));
    v.s5 = f2bf(fast_tanh(e1.y + p1.y));
    v.s6 = f2bf(fast_tanh(e1.z + p1.z));
    v.s7 = f2bf(fast_tanh(e1.w + p1.w));
    *(ushort8v*)(jbuf + (size_t)m * JDIM + c8) = v;
}

// ---------------------------------------------------------------------------
// Pure bf16 GEMM: out = A @ Wt^T + b_out   (round-3 K-loop, measured 464 total)
// BM=BN=128, BK=64, 2-buffer prefetch, vmcnt(0)+s_barrier per tile.
// T2 swizzle (8 chunks/row): src chunk = slot^(row&7); read slot =
// ((kk>>3)+quad)^(lm&7).
//
// SINGLE CHANGE vs round-3: epilogue. Round-8 taught us (WRITE_SIZE 1.16 GB
// = 3.54x ideal) that NT stores MUST be wave-contiguous: partial 64B HBM
// granules don't combine across instructions under NT. New epilogue:
//   acc -> epi[row][132] via b32 writes (banks: 16 consecutive cols x quad
//   offset 16 -> 2-way = free), barrier, then 16 passes where a 32-lane
//   group reads b128 along a row (sequential banks, conflict-free) and
//   NT-stores 32 x 16B = 512 B CONTIGUOUS of one output row -> full 64B
//   granules -> no write amplification (expect ~330 MB vs round-3's 418).
// ---------------------------------------------------------------------------
#define GBM 128
#define GBN 128
#define GBK 64
#define NBN (VOCAB / GBN)     // 8
#define NTILES (JDIM / GBK)   // 10
#define EPI_LD 132            // floats per row (128 + 4 pad)

__global__ __launch_bounds__(256, 2)
void gemm_joint(const unsigned short* __restrict__ A,
                const unsigned short* __restrict__ Wt,
                const float* __restrict__ bout,
                float* __restrict__ out)
{
    // union: staging 2x16KB (A) + 2x16KB (B) = 64 KB; epi 128*132*4 = 66 KB
    __shared__ __align__(16) unsigned char smem[GBM * EPI_LD * 4];  // 67584 B
    unsigned short* asB = (unsigned short*)smem;        // [2][128*64]
    unsigned short* bsB = asB + 2 * GBM * GBK;          // [2][128*64]
    float* epi = (float*)smem;                          // [128][132]

    const int tid = threadIdx.x;

    // XCD-aware swizzle (bijective: gridDim.x = nbm*8, always % 8 == 0).
    const int cpx = gridDim.x >> 3;
    const int bid = blockIdx.x;
    const int swz = (bid & 7) * cpx + (bid >> 3);
    const int bm = swz >> 3;          // NBN == 8
    const int bn = swz & (NBN - 1);

    // staging: thread covers row (tid>>3)+32r, chunk tid&7 (16B);
    // LDS dst = tid*16B + r*4KB (lane-linear); global chunk pre-XOR'd.
    const int srow = tid >> 3;        // 0..31
    const int schunk = tid & 7;       // 16B chunk slot
    const int scolSwz = (schunk ^ (srow & 7)) * 8;
    const unsigned short* aBase = A  + (size_t)(bm * GBM + srow) * JDIM + scolSwz;
    const unsigned short* bBase = Wt + (size_t)(bn * GBN + srow) * JDIM + scolSwz;
    const int ldsOff = tid * 8;       // shorts

    const int wave = tid >> 6, lane = tid & 63;
    const int wm = (wave >> 1) * 64, wn = (wave & 1) * 64;
    const int lm = lane & 15, quad = lane >> 4;
    const int rx = lm & 7;            // row&7 for this lane's fragment rows

    // bias per j-frag (col = bn*128 + wn + j*16 + lm)
    float biasj[4];
    #pragma unroll
    for (int j = 0; j < 4; ++j)
        biasj[j] = bout[bn * GBN + wn + j * 16 + lm];

    float4v acc[4][4];
    #pragma unroll
    for (int i = 0; i < 4; ++i)
        #pragma unroll
        for (int j = 0; j < 4; ++j)
            acc[i][j] = (float4v){0.f, 0.f, 0.f, 0.f};

#define STAGE(buf, k0)                                                          \
    {                                                                           \
        _Pragma("unroll")                                                       \
        for (int r = 0; r < 4; ++r) {                                           \
            gload_lds16(aBase + (size_t)(r * 32) * JDIM + (k0),                 \
                        asB + (buf) * (GBM * GBK) + ldsOff + r * 2048);         \
            gload_lds16(bBase + (size_t)(r * 32) * JDIM + (k0),                 \
                        bsB + (buf) * (GBM * GBK) + ldsOff + r * 2048);         \
        }                                                                       \
    }

#define COMPUTE(buf)                                                            \
    {                                                                           \
        _Pragma("unroll")                                                       \
        for (int kk = 0; kk < GBK; kk += 32) {                                  \
            const int cp = (((kk >> 3) + quad) ^ rx) * 8;                       \
            short8 a[4], b[4];                                                  \
            _Pragma("unroll")                                                   \
            for (int i = 0; i < 4; ++i)                                         \
                a[i] = *(const short8*)(asB + (buf) * (GBM * GBK) + (wm + i * 16 + lm) * GBK + cp); \
            _Pragma("unroll")                                                   \
            for (int j = 0; j < 4; ++j)                                         \
                b[j] = *(const short8*)(bsB + (buf) * (GBM * GBK) + (wn + j * 16 + lm) * GBK + cp); \
            _Pragma("unroll")                                                   \
            for (int i = 0; i < 4; ++i)                                         \
                _Pragma("unroll")                                               \
                for (int j = 0; j < 4; ++j)                                     \
                    acc[i][j] = __builtin_amdgcn_mfma_f32_16x16x32_bf16(a[i], b[j], acc[i][j], 0, 0, 0); \
        }                                                                       \
    }

    // prologue
    STAGE(0, 0);
    asm volatile("s_waitcnt vmcnt(0)" ::: "memory");
    __builtin_amdgcn_s_barrier();

    int cur = 0;
    for (int t = 0; t < NTILES - 1; ++t) {
        STAGE(cur ^ 1, (t + 1) * GBK);           // issue next-tile loads FIRST
        COMPUTE(cur);                            // ds_read + MFMA on current
        asm volatile("s_waitcnt vmcnt(0)" ::: "memory");
        __builtin_amdgcn_s_barrier();
        cur ^= 1;
    }
    COMPUTE(cur);                                // last tile (no prefetch)

#undef STAGE
#undef COMPUTE

    // ---- epilogue: LDS transpose -> wave-contiguous NT stores ----
    __syncthreads();   // all waves done reading staging LDS (union with epi)

    #pragma unroll
    for (int i = 0; i < 4; ++i)
        #pragma unroll
        for (int j = 0; j < 4; ++j) {
            // C/D map: row = wm + i*16 + quad*4 + rr, col = wn + j*16 + lm
            #pragma unroll
            for (int rr = 0; rr < 4; ++rr)
                epi[(wm + i * 16 + quad * 4 + rr) * EPI_LD + wn + j * 16 + lm]
                    = acc[i][j][rr] + biasj[j];
        }

    __syncthreads();

    // read back: pass p covers rows p*8 .. p*8+7; thread -> row p*8+(tid>>5),
    // 16B chunk tid&31. A 32-lane group stores 512 B contiguous of one row.
    {
        const int rrow = tid >> 5;        // 0..7
        const int chunk = tid & 31;       // 0..31 (x 16 B)
        #pragma unroll
        for (int p = 0; p < 16; ++p) {
            const int row = p * 8 + rrow;
            float4v v = *(const float4v*)&epi[row * EPI_LD + chunk * 4];
            __builtin_nontemporal_store(v,
                (float4v*)(out + (size_t)(bm * GBM + row) * VOCAB + bn * GBN + chunk * 4));
        }
    }
}

// ---------------------------------------------------------------------------
// Fallback (ws too small): fused kernel — tanh recomputed per N-tile.
// ---------------------------------------------------------------------------
#define BM 128
#define BN 128
#define BK 64
#define LDST 72

__global__ __launch_bounds__(256, 2)
void joint_gemm_fused(const float* __restrict__ encp, const float* __restrict__ predp,
                      const unsigned short* __restrict__ Wt, const float* __restrict__ bout,
                      float* __restrict__ out)
{
    __shared__ __align__(16) unsigned short As[BM * LDST];
    __shared__ __align__(16) unsigned short Bs[BN * LDST];
    const int tid = threadIdx.x;
    const int bm = blockIdx.x, bn = blockIdx.y;
    const int rbase = tid >> 4;
    const int c4 = (tid & 15) * 4;
    int encOff[8], predOff[8];
    #pragma unroll
    for (int i = 0; i < 8; ++i) {
        int mg  = bm * BM + i * 16 + rbase;
        int b   = mg / (T_ * U_);
        int rem = mg - b * (T_ * U_);
        int t   = rem / U_;
        int u   = rem - t * U_;
        encOff[i]  = (b * T_ + t) * JDIM + c4;
        predOff[i] = (b * U_ + u) * JDIM + c4;
    }
    const int nrow = tid >> 3;
    const int bk8  = (tid & 7) * 8;
    const size_t wtBase = (size_t)(bn * BN) * JDIM;
    const int wave = tid >> 6, lane = tid & 63;
    const int wm = (wave >> 1) * 64, wn = (wave & 1) * 64;
    const int lm = lane & 15, quad = lane >> 4;

    float4v acc[4][4];
    #pragma unroll
    for (int i = 0; i < 4; ++i)
        #pragma unroll
        for (int j = 0; j < 4; ++j)
            acc[i][j] = (float4v){0.f, 0.f, 0.f, 0.f};

    for (int k0 = 0; k0 < JDIM; k0 += BK) {
        #pragma unroll
        for (int i = 0; i < 8; ++i) {
            int row = i * 16 + rbase;
            float4v e4 = *(const float4v*)(encp + encOff[i] + k0);
            float4v p4 = *(const float4v*)(predp + predOff[i] + k0);
            ushort4v v;
            v.x = f2bf(fast_tanh(e4.x + p4.x));
            v.y = f2bf(fast_tanh(e4.y + p4.y));
            v.z = f2bf(fast_tanh(e4.z + p4.z));
            v.w = f2bf(fast_tanh(e4.w + p4.w));
            *(ushort4v*)(&As[row * LDST + c4]) = v;
        }
        #pragma unroll
        for (int i = 0; i < 4; ++i) {
            int n = i * 32 + nrow;
            float4v w = *(const float4v*)((const float*)(Wt + wtBase + (size_t)n * JDIM + k0 + bk8));
            *(float4v*)(&Bs[n * LDST + bk8]) = w;
        }
        __syncthreads();
        #pragma unroll
        for (int kk = 0; kk < BK; kk += 32) {
            short8 a[4], b[4];
            #pragma unroll
            for (int i = 0; i < 4; ++i)
                a[i] = *(const short8*)(&As[(wm + i * 16 + lm) * LDST + kk + quad * 8]);
            #pragma unroll
            for (int j = 0; j < 4; ++j)
                b[j] = *(const short8*)(&Bs[(wn + j * 16 + lm) * LDST + kk + quad * 8]);
            #pragma unroll
            for (int i = 0; i < 4; ++i)
                #pragma unroll
                for (int j = 0; j < 4; ++j)
                    acc[i][j] = __builtin_amdgcn_mfma_f32_16x16x32_bf16(a[i], b[j], acc[i][j], 0, 0, 0);
        }
        __syncthreads();
    }
    #pragma unroll
    for (int j = 0; j < 4; ++j) {
        int ng = bn * BN + wn + j * 16 + lm;
        float bias = bout[ng];
        #pragma unroll
        for (int i = 0; i < 4; ++i) {
            int mg0 = bm * BM + wm + i * 16 + quad * 4;
            #pragma unroll
            for (int r = 0; r < 4; ++r)
                out[(size_t)(mg0 + r) * VOCAB + ng] = acc[i][j][r] + bias;
        }
    }
}

// ---------------------------------------------------------------------------
extern "C" void kernel_launch(void* const* d_in, const int* in_sizes, int n_in,
                              void* d_out, int out_size, void* d_ws, size_t ws_size,
                              hipStream_t stream) {
    const float* enc_out  = (const float*)d_in[0];  // [4,200,512]
    const float* pred_out = (const float*)d_in[1];  // [4,100,512]
    const float* W_enc    = (const float*)d_in[2];  // [512,640]
    const float* b_enc    = (const float*)d_in[3];  // [640]
    const float* W_pred   = (const float*)d_in[4];  // [512,640]
    const float* W_out    = (const float*)d_in[5];  // [640,1024]
    const float* b_out    = (const float*)d_in[6];  // [1024]
    float* out = (float*)d_out;

    float* encp  = (float*)d_ws;                                 // 800*640 fp32
    float* predp = encp + 800 * JDIM;                            // 400*640 fp32
    unsigned short* Wt = (unsigned short*)(predp + 400 * JDIM);  // 1024*640 bf16
    unsigned short* jbuf = Wt + (size_t)VOCAB * JDIM;            // chunked joint bf16

    const size_t fixedBytes = (800 * JDIM + 400 * JDIM) * sizeof(float)
                            + (size_t)VOCAB * JDIM * sizeof(unsigned short);

    prep<<<dim3(PREP_BLOCKS), 256, 0, stream>>>(enc_out, pred_out, W_enc, b_enc,
                                                W_pred, W_out, encp, predp, Wt);

    size_t avail = ws_size > fixedBytes ? ws_size - fixedBytes : 0;
    long mcMax = (long)(avail / (JDIM * sizeof(unsigned short)));
    mcMax = (mcMax / 128) * 128;
    if (mcMax > M_TOTAL) mcMax = M_TOTAL;

    if (mcMax >= 8192) {
        for (int m0 = 0; m0 < M_TOTAL; m0 += (int)mcMax) {
            int mc = M_TOTAL - m0 < mcMax ? M_TOTAL - m0 : (int)mcMax;  // always mult of 128
            int nThreads = mc * (JDIM / 8);
            joint_tanh<<<(nThreads + 255) / 256, 256, 0, stream>>>(encp, predp, jbuf, m0, mc);
            gemm_joint<<<dim3((mc / GBM) * NBN), 256, 0, stream>>>(jbuf, Wt, b_out,
                                                                   out + (size_t)m0 * VOCAB);
        }
    } else {
        // scratch too small for materialization — fused path
        joint_gemm_fused<<<dim3(M_TOTAL / BM, VOCAB / BN), 256, 0, stream>>>(encp, predp, Wt, b_out, out);
    }
}